// Round 3
// baseline (540.182 us; speedup 1.0000x reference)
//
#include <hip/hip_runtime.h>
#include <cstddef>
#include <cstdint>

// ---------------- problem constants ----------------
constexpr int DM = 1024;      // D_MODEL
constexpr int DI = 2048;      // D_INNER
constexpr int DS = 16;        // D_STATE
constexpr int NH = 8;         // NHEADS
constexpr int CD = 2080;      // CONV_DIM
constexpr int DP = 4136;      // D_IN_PROJ
constexpr int DPT = 4352;     // DP padded to 17*256 (W_in^T rows)
constexpr int Q  = 64;        // CHUNK
constexpr int B_ = 4;         // BATCH
constexpr int L_ = 4096;      // SEQLEN
constexpr int NCH = 64;       // chunks per sequence
constexpr int HP = 256;       // HEADDIM
constexpr int NR = B_ * L_;   // 16384 rows

// ---------------- workspace layout (BYTE offsets) ----------------
constexpr size_t AL(size_t x) { return (x + 255) & ~(size_t)255; }
constexpr size_t OFFB_ZX = 0;                                   // zxbcdt bf16 (NR x DP)
constexpr size_t OFFB_BC = AL(OFFB_ZX + (size_t)NR * DP * 2);   // conv'd B,C fp32 (NR x 32)
constexpr size_t OFFB_DT = AL(OFFB_BC + (size_t)NR * 32 * 4);   // dt fp32 (NR x NH)
constexpr size_t OFFB_CS = AL(OFFB_DT + (size_t)NR * NH * 4);   // cumsum fp32
constexpr size_t OFFB_ST = AL(OFFB_CS + (size_t)B_ * NCH * NH * Q * 4); // states fp32 (aliases u_bf16)
constexpr size_t OFFB_Y  = AL(OFFB_ST + (size_t)B_ * NCH * NH * HP * DS * 4); // y bf16 (aliases W_in^T bf16)
constexpr size_t OFFB_WO = AL(OFFB_Y + (size_t)NR * DI * 2);    // W_out^T bf16 (1024 x 2048)

__device__ __forceinline__ float silu_f(float x) { return x / (1.f + expf(-x)); }
__device__ __forceinline__ float bf2f(unsigned short v) {
  unsigned int u = ((unsigned int)v) << 16;
  return __builtin_bit_cast(float, u);
}
__device__ __forceinline__ unsigned short f2bf(float f) {
  unsigned int u = __builtin_bit_cast(unsigned int, f);
  u += 0x7FFFu + ((u >> 16) & 1u);   // round-to-nearest-even
  return (unsigned short)(u >> 16);
}

typedef __attribute__((ext_vector_type(8))) short bf16x8;   // 8 bf16 = 4 VGPRs
typedef __attribute__((ext_vector_type(4))) float f32x4;

__device__ __forceinline__ void bar() {
  asm volatile("" ::: "memory");
  __builtin_amdgcn_s_barrier();
  asm volatile("" ::: "memory");
}

// ================= 256x256 deep-pipelined MFMA bf16 GEMM =================
// C[M,N] = A[M,K] @ Bt[N,K]^T.  BM=BN=256, 8 waves (2Mx4N), 512 threads.
// LDS: ring of 4 K-slots (32 wide): each slot = A 256x32 + B 256x32 bf16 = 32 KB
// -> 128 KB total, 1 block/CU, 2 waves/SIMD.
// Schedule per slot s (2 phases):
//   [vmcnt(8); barrier]  <- slot s landed (8 loads = slots s+1,s+2 in flight)
//   phase even: ds_read B frags + A frags(rows-half0); issue A-stage slot s+3; 16 MFMA
//   phase odd : ds_read A frags(rows-half1) (B reused);  issue B-stage slot s+3; 16 MFMA
//   [barrier]
// Ring slot (s+3)&3 == (s-1)&3 -> stage/read regions always disjoint; vmcnt
// never drained to 0 in the main loop (T3+T4).
//
// LDS bank swizzle (R2 fix: was 2-bit XOR on 64B rows -> 4-way conflict,
// 1.34e7 conflict-cycles): slot rows are 64B (32 bf16); a PAIR of rows forms
// one 128B bank line with eight 16B slots s = (r&1)*4 + c16. Physical slot
// s' = s ^ ((r>>1)&7). Per 16-lane ds_read_b128 group (16 consecutive rows,
// fixed quad) every 16B slot mod 128B is hit exactly 2x -> 2-way = free (m136).
// Applied on BOTH sides: pre-swizzled global source in stage(), swizzled
// address in fragment reads (rule #21, same involution).
template<bool OUT_BF16>
__global__ __launch_bounds__(512, 2)
void gemm256(const unsigned short* __restrict__ A, const unsigned short* __restrict__ Bt,
             void* __restrict__ Cout, int M, int N, int K, int ldc) {
  __shared__ __align__(16) unsigned short ring[4][2][256 * 32];   // [slot][A/B][8192]
  const int t = threadIdx.x;
  const int w = t >> 6, l = t & 63;
  const int quad = l >> 4, lan = l & 15;
  const int wm = w >> 2, wn = w & 3;            // 2 x 4 wave grid
  // XCD-aware remap (bijective: gridDim.y % 8 == 0)
  const int ncol = gridDim.x;
  const int id = blockIdx.y * ncol + blockIdx.x;
  const int xcd = id & 7, slot0 = id >> 3;
  const int rpx = gridDim.y >> 3;
  const int row_g = xcd * rpx + slot0 / ncol;
  const int col_g = slot0 - (slot0 / ncol) * ncol;
  const int row0 = row_g * 256, col0 = col_g * 256;

  const int NSLOT = K >> 5;

  // stage one 16KB piece (mat 0 = A-slice, 1 = B-slice) of K-slot s.
  // Linear LDS dest chunk f -> logical (row, 16B-chunk) via the inverse
  // pair-line swizzle; global source fetched from there.
  auto stage = [&](int s, int mat) {
    const int ss = (s < NSLOT) ? s : 0;         // clamp: tail stages never read
    const unsigned short* G = mat ? Bt : A;
    const int b0 = mat ? col0 : row0;
    unsigned short* lb = ring[s & 3][mat];
    const int k0 = ss << 5;
    #pragma unroll
    for (int i = 0; i < 2; ++i) {
      const int f = i * 512 + t;                // 16B chunk index 0..1023
      const int pair = f >> 3, sp = f & 7;      // 128B line, physical slot
      const int sl = sp ^ (pair & 7);           // logical slot
      const int r = pair * 2 + (sl >> 2);       // logical row 0..255
      const int c16 = sl & 3;                   // logical 16B chunk in row
      const unsigned short* gp = G + (size_t)(b0 + r) * K + k0 + (c16 << 3);
      __builtin_amdgcn_global_load_lds(
          (const __attribute__((address_space(1))) void*)gp,
          (__attribute__((address_space(3))) void*)(lb + (size_t)f * 8), 16, 0, 0);
    }
  };

  // swizzled fragment read: logical (row r, 16B-chunk q) of a slot matrix
  auto frag = [&](const unsigned short* base, int r, int q) -> bf16x8 {
    const int pair = r >> 1;
    const int sp = (((r & 1) << 2) | q) ^ (pair & 7);
    return *(const bf16x8*)&base[pair * 64 + sp * 8];
  };

  f32x4 acc[2][4][4];
  #pragma unroll
  for (int rq = 0; rq < 2; ++rq)
    #pragma unroll
    for (int mi = 0; mi < 4; ++mi)
      #pragma unroll
      for (int ni = 0; ni < 4; ++ni)
        acc[rq][mi][ni] = (f32x4)(0.0f);

  // prologue: slots 0,1,2 in flight (12 load instructions per wave)
  stage(0, 0); stage(0, 1);
  stage(1, 0); stage(1, 1);
  stage(2, 0); stage(2, 1);

  for (int s = 0; s < NSLOT; ++s) {
    asm volatile("s_waitcnt vmcnt(8)" ::: "memory");  // slot s landed (own wave)
    bar();                                            // -> landed for ALL waves
    const unsigned short* Aslot = ring[s & 3][0];
    const unsigned short* Bslot = ring[s & 3][1];
    bf16x8 af[4], bf[4];
    // ---- phase even: rows-half 0 ----
    #pragma unroll
    for (int ni = 0; ni < 4; ++ni)
      bf[ni] = frag(Bslot, wn * 64 + ni * 16 + lan, quad);
    #pragma unroll
    for (int mi = 0; mi < 4; ++mi)
      af[mi] = frag(Aslot, wm * 128 + mi * 16 + lan, quad);
    stage(s + 3, 0);                                  // A-slice of slot s+3
    __builtin_amdgcn_s_setprio(1);
    #pragma unroll
    for (int mi = 0; mi < 4; ++mi)
      #pragma unroll
      for (int ni = 0; ni < 4; ++ni)
        acc[0][mi][ni] = __builtin_amdgcn_mfma_f32_16x16x32_bf16(af[mi], bf[ni], acc[0][mi][ni], 0, 0, 0);
    __builtin_amdgcn_s_setprio(0);
    // ---- phase odd: rows-half 1 (B frags reused) ----
    #pragma unroll
    for (int mi = 0; mi < 4; ++mi)
      af[mi] = frag(Aslot, wm * 128 + 64 + mi * 16 + lan, quad);
    stage(s + 3, 1);                                  // B-slice of slot s+3
    __builtin_amdgcn_s_setprio(1);
    #pragma unroll
    for (int mi = 0; mi < 4; ++mi)
      #pragma unroll
      for (int ni = 0; ni < 4; ++ni)
        acc[1][mi][ni] = __builtin_amdgcn_mfma_f32_16x16x32_bf16(af[mi], bf[ni], acc[1][mi][ni], 0, 0, 0);
    __builtin_amdgcn_s_setprio(0);
    bar();                                            // slot-s reads drained
  }
  asm volatile("s_waitcnt vmcnt(0)" ::: "memory");    // drain tail LDS-DMA

  // ---- epilogue ----
  #pragma unroll
  for (int rq = 0; rq < 2; ++rq)
    #pragma unroll
    for (int mi = 0; mi < 4; ++mi) {
      const size_t rb = row0 + wm * 128 + rq * 64 + mi * 16 + quad * 4;
      #pragma unroll
      for (int ni = 0; ni < 4; ++ni) {
        const int colb = col0 + wn * 64 + ni * 16 + lan;
        if (colb < N) {
          if constexpr (OUT_BF16) {
            unsigned short* C = (unsigned short*)Cout;
            #pragma unroll
            for (int r = 0; r < 4; ++r)
              C[(rb + r) * (size_t)ldc + colb] = f2bf(acc[rq][mi][ni][r]);
          } else {
            float* C = (float*)Cout;
            #pragma unroll
            for (int r = 0; r < 4; ++r)
              C[(rb + r) * (size_t)ldc + colb] = acc[rq][mi][ni][r];
          }
        }
      }
    }
}

// ---------------- fp32 -> bf16 elementwise convert ----------------
__global__ __launch_bounds__(256)
void cvt_bf16(const float* __restrict__ src, unsigned short* __restrict__ dst, size_t n4) {
  const size_t i = ((size_t)blockIdx.x * 256 + threadIdx.x) * 4;
  if (i < n4 * 4) {
    float4 v = *(const float4*)(src + i);
    ushort4 o;
    o.x = f2bf(v.x); o.y = f2bf(v.y); o.z = f2bf(v.z); o.w = f2bf(v.w);
    *(ushort4*)(dst + i) = o;
  }
}

// ---------------- fp32 [R][C] -> bf16 transposed [Cpad][R], zero-fill c>=Cvalid ----------------
__global__ __launch_bounds__(256)
void transpose_cvt(const float* __restrict__ src, unsigned short* __restrict__ dst,
                   int R, int C, int Cvalid) {
  __shared__ float T[64][65];
  const int t = threadIdx.x;
  const int n0 = blockIdx.x * 64, k0 = blockIdx.y * 64;
  #pragma unroll
  for (int i = 0; i < 4; ++i) {
    int f = t + i * 256;
    int r = f >> 4, c4 = (f & 15) << 2;
    int n = n0 + c4;
    float4 v = make_float4(0.f, 0.f, 0.f, 0.f);
    if (n + 3 < Cvalid) {
      v = *(const float4*)(src + (size_t)(k0 + r) * C + n);
    } else {
      if (n + 0 < Cvalid) v.x = src[(size_t)(k0 + r) * C + n + 0];
      if (n + 1 < Cvalid) v.y = src[(size_t)(k0 + r) * C + n + 1];
      if (n + 2 < Cvalid) v.z = src[(size_t)(k0 + r) * C + n + 2];
      if (n + 3 < Cvalid) v.w = src[(size_t)(k0 + r) * C + n + 3];
    }
    T[r][c4 + 0] = v.x; T[r][c4 + 1] = v.y; T[r][c4 + 2] = v.z; T[r][c4 + 3] = v.w;
  }
  __syncthreads();
  #pragma unroll
  for (int i = 0; i < 4; ++i) {
    int f = t + i * 256;
    int c = f >> 4, r4 = (f & 15) << 2;
    ushort4 o;
    o.x = f2bf(T[r4 + 0][c]); o.y = f2bf(T[r4 + 1][c]);
    o.z = f2bf(T[r4 + 2][c]); o.w = f2bf(T[r4 + 3][c]);
    *(ushort4*)(dst + (size_t)(n0 + c) * R + k0 + r4) = o;
  }
}

// ---------------- conv+SiLU for the 32 B/C channels only ----------------
__global__ __launch_bounds__(256)
void convbc_kernel(const unsigned short* __restrict__ zx, const float* __restrict__ cw,
                   const float* __restrict__ cb, float* __restrict__ bc) {
  const int idx = blockIdx.x * 256 + threadIdx.x;   // < NR*32
  const int j = idx & 31;
  const int row = idx >> 5;
  const int l = row & (L_ - 1);
  const int cc = DI + j;                            // xBC channel 2048+j
  float a = cb[cc];
  #pragma unroll
  for (int k = 0; k < 4; ++k) {
    int ll = l - 3 + k;
    if (ll >= 0)
      a += bf2f(zx[(size_t)(row - 3 + k) * DP + (DI + DI + j)]) * cw[cc * 4 + k];
  }
  bc[(size_t)row * 32 + j] = silu_f(a);
}

// ---------------- dt = softplus(raw + bias) ----------------
__global__ __launch_bounds__(256)
void dt_kernel(const unsigned short* __restrict__ zx, const float* __restrict__ dt_bias,
               float* __restrict__ dt) {
  const int i = blockIdx.x * 256 + threadIdx.x;   // < NR*NH
  const int h = i & 7;
  const size_t row = (size_t)(i >> 3);
  float x = bf2f(zx[row * DP + (DI + CD) + h]) + dt_bias[h];
  dt[i] = (x > 20.f) ? x : log1pf(expf(x));
}

// ---------- per-(b,chunk,head): scan-cumsum + x-conv + MFMA Y_diag(+Dx) + MFMA states ----------
__global__ __launch_bounds__(256)
void chunk_kernel(const unsigned short* __restrict__ zx, const float* __restrict__ bc,
                  const float* __restrict__ dt, const float* __restrict__ A_log,
                  const float* __restrict__ cw, const float* __restrict__ cb,
                  const float* __restrict__ Dp, float* __restrict__ cs_out,
                  float* __restrict__ states, unsigned short* __restrict__ yb) {
  const int c = blockIdx.x, h = blockIdx.y, b = blockIdx.z;
  const int t = threadIdx.x;
  const int w = t >> 6, l = t & 63;
  const int quad = l >> 4, lan = l & 15;
  __shared__ float dtS[Q], csS[Q], ddS[Q];
  __shared__ float BsS[Q][DS + 1];
  __shared__ __align__(16) unsigned short Msd[Q][Q + 8];   // bf16 [q][s]
  __shared__ __align__(16) unsigned short BdT[DS][Q + 8];  // bf16 [n][q] = B[q][n]*dd[q]
  __shared__ __align__(16) char regionA[Q * (Q + 8) * 2];           // {CsS | xsT}
  __shared__ __align__(16) char regionB[Q * DS * 4 + Q * (Q + 8) * 2]; // {rawS | stS+ytS}
  float (*CsS)[DS]                 = (float(*)[DS])regionA;
  unsigned short (*xsT)[Q + 8]     = (unsigned short(*)[Q + 8])regionA;
  unsigned short (*rawS)[Q]        = (unsigned short(*)[Q])regionB;
  float (*stS)[DS]                 = (float(*)[DS])regionB;
  unsigned short (*ytS)[Q + 8]     = (unsigned short(*)[Q + 8])(regionB + Q * DS * 4);
  const size_t rowb = (size_t)b * L_ + (size_t)c * Q;

  // ---- dt load + parallel inclusive scan (wave 0) ----
  if (t < Q) {
    float dtv = dt[(rowb + t) * NH + h];
    dtS[t] = dtv;
    float s = dtv * (-expf(A_log[h]));
    #pragma unroll
    for (int off = 1; off < 64; off <<= 1) {
      float n = __shfl_up(s, off, 64);
      if (t >= off) s += n;
    }
    csS[t] = s;
    float slast = __shfl(s, 63, 64);
    ddS[t] = expf(slast - s) * dtv;          // decay_states * dt
    cs_out[(((size_t)b * NCH + c) * NH + h) * Q + t] = s;
  }
  for (int i = t; i < Q * DS; i += 256) {    // B/C loads (independent of scan)
    int q = i >> 4, n = i & 15;
    BsS[q][n] = bc[(rowb + q) * 32 + n];
    CsS[q][n] = bc[(rowb + q) * 32 + 16 + n];
  }
  __syncthreads();
  // ---- BdT + Msd (bf16) ----
  for (int i = t; i < DS * Q; i += 256) {
    int n = i & 15, q = i >> 4;
    BdT[n][q] = f2bf(BsS[q][n] * ddS[q]);
  }
  const float Dh = Dp[h];
  for (int i = t; i < Q * Q; i += 256) {
    int q = i >> 6, s = i & 63;
    float v = 0.f;
    if (s <= q) {
      float d = 0.f;
      #pragma unroll
      for (int n = 0; n < DS; ++n) d += CsS[q][n] * BsS[s][n];
      v = expf(csS[q] - csS[s]) * d * dtS[s];
      if (s == q) v += Dh;
    }
    Msd[q][s] = f2bf(v);
  }

  // ---- raw x prefetch (67 rows x 64 cols bf16 = 536 uint4 chunks) ----
  const int pch = l;                         // conv channel within tile (0..63)
  uint4 r0 = make_uint4(0, 0, 0, 0), r1 = make_uint4(0, 0, 0, 0), r2 = make_uint4(0, 0, 0, 0);
  {
    const int col0 = DI + h * HP;            // pt = 0
    const unsigned short* gb = zx + ((size_t)b * L_ + (c * Q - 3)) * DP + col0;
    if (c > 0 || t >= 24) r0 = *(const uint4*)(gb + (size_t)(t >> 3) * DP + (t & 7) * 8);
    r1 = *(const uint4*)(gb + (size_t)((t + 256) >> 3) * DP + (t & 7) * 8);
    if (t < 24) r2 = *(const uint4*)(gb + (size_t)((t + 512) >> 3) * DP + (t & 7) * 8);
  }

  for (int pt = 0; pt < 4; ++pt) {
    uint4* rw = (uint4*)rawS;
    rw[t] = r0; rw[t + 256] = r1;
    if (t < 24) rw[t + 512] = r2;
    __syncthreads();                          // B1: rawS ready
    // ---- conv+silu -> xsT[p][q] ----
    {
      const int cc = h * HP + pt * Q + pch;
      const float w0 = cw[cc * 4 + 0], w1 = cw[cc * 4 + 1];
      const float w2 = cw[cc * 4 + 2], w3 = cw[cc * 4 + 3];
      const float bias = cb[cc];
      const int q0 = w * 16;
      unsigned short ob[16];
      #pragma unroll
      for (int i2 = 0; i2 < 16; ++i2) {
        int q = q0 + i2;
        float a = bias + bf2f(rawS[q][pch]) * w0 + bf2f(rawS[q + 1][pch]) * w1
                       + bf2f(rawS[q + 2][pch]) * w2 + bf2f(rawS[q + 3][pch]) * w3;
        ob[i2] = f2bf(silu_f(a));
      }
      *(uint4*)&xsT[pch][q0 + 0] = *(uint4*)&ob[0];
      *(uint4*)&xsT[pch][q0 + 8] = *(uint4*)&ob[8];
    }
    // ---- prefetch next pt's raw tile (hides behind MFMA phase) ----
    if (pt < 3) {
      const int col0n = DI + h * HP + (pt + 1) * Q;
      const unsigned short* gb = zx + ((size_t)b * L_ + (c * Q - 3)) * DP + col0n;
      r0 = make_uint4(0, 0, 0, 0); r2 = make_uint4(0, 0, 0, 0);
      if (c > 0 || t >= 24) r0 = *(const uint4*)(gb + (size_t)(t >> 3) * DP + (t & 7) * 8);
      r1 = *(const uint4*)(gb + (size_t)((t + 256) >> 3) * DP + (t & 7) * 8);
      if (t < 24) r2 = *(const uint4*)(gb + (size_t)((t + 512) >> 3) * DP + (t & 7) * 8);
    }
    __syncthreads();                          // B2: xsT ready, rawS consumed
    // ---- MFMA phase ----
    bf16x8 xfrag[2];
    #pragma unroll
    for (int ks = 0; ks < 2; ++ks)
      xfrag[ks] = *(const bf16x8*)&xsT[w * 16 + lan][quad * 8 + ks * 32];
    {  // states[p][n] = sum_q x[p][q] * BdT[n][q] -> stS
      f32x4 sacc = (f32x4)(0.0f);
      #pragma unroll
      for (int ks = 0; ks < 2; ++ks) {
        bf16x8 bfr = *(const bf16x8*)&BdT[lan][quad * 8 + ks * 32];
        sacc = __builtin_amdgcn_mfma_f32_16x16x32_bf16(xfrag[ks], bfr, sacc, 0, 0, 0);
      }
      #pragma unroll
      for (int r = 0; r < 4; ++r)
        stS[w * 16 + quad * 4 + r][lan] = sacc[r];
    }
    {  // Y_diag[q][p] = sum_s Msd[q][s]*x[p][s] -> ytS
      #pragma unroll
      for (int mi = 0; mi < 4; ++mi) {
        f32x4 yac = (f32x4)(0.0f);
        #pragma unroll
        for (int ks = 0; ks < 2; ++ks) {
          bf16x8 am = *(const bf16x8*)&Msd[mi * 16 + lan][quad * 8 + ks * 32];
          yac = __builtin_amdgcn_mfma_f32_16x16x32_bf16(am, xfrag[ks], yac, 0, 0, 0);
        }
        #pragma unroll
        for (int r = 0; r < 4; ++r)
          ytS[mi * 16 + quad * 4 + r][w * 16 + lan] = f2bf(yac[r]);
      }
    }
    __syncthreads();                          // B3: staging tiles complete
    // ---- coalesced global stores ----
    {  // states tile: 64p x 16n fp32, fully contiguous 4KB
      const size_t stbase = ((((size_t)b * NCH + c) * NH + h) * HP + (size_t)pt * Q) * DS;
      ((float4*)(states + stbase))[t] = ((const float4*)&stS[0][0])[t];
    }
    {  // y tile: 64 rows x 128B
      const int colbase = h * HP + pt * Q;
      #pragma unroll
      for (int pass = 0; pass < 2; ++pass) {
        int q = pass * 32 + (t >> 3), p8 = (t & 7) * 8;
        *(uint4*)(yb + (rowb + q) * (size_t)DI + colbase + p8) = *(const uint4*)&ytS[q][p8];
      }
    }
    __syncthreads();                          // B4: stS/ytS reads done before next rawS write
  }
}

// ---------------- sequential inter-chunk scan (in place: states -> prev) ----------------
__global__ __launch_bounds__(256)
void scan_kernel(float* __restrict__ states, const float* __restrict__ cs) {
  const int pn = blockIdx.x * 256 + threadIdx.x;
  const int h = blockIdx.y, b = blockIdx.z;
  const size_t cstride = (size_t)NH * HP * DS;
  const size_t base = ((size_t)b * NCH * NH + h) * (size_t)(HP * DS) + pn;
  float carry = 0.f;
  for (int c = 0; c < NCH; ++c) {
    float dec = expf(cs[(((size_t)b * NCH + c) * NH + h) * Q + (Q - 1)]);
    float st = states[base + (size_t)c * cstride];
    states[base + (size_t)c * cstride] = carry;
    carry = dec * carry + st;
  }
}

// ---------------- Y_off accumulation into bf16 y ----------------
__global__ __launch_bounds__(256)
void yoff_kernel(const float* __restrict__ bc, const float* __restrict__ cs,
                 const float* __restrict__ prev, unsigned short* __restrict__ yb) {
  const int c = blockIdx.x, h = blockIdx.y, b = blockIdx.z;
  const int t = threadIdx.x;
  __shared__ __align__(16) float CsS[Q][DS];
  __shared__ float ecs[Q];
  const size_t rowb = (size_t)b * L_ + (size_t)c * Q;
  const size_t pb = (((size_t)b * NCH + c) * NH + h) * (size_t)(HP * DS);
  for (int i = t; i < Q * DS; i += 256) {
    int q = i >> 4, n = i & 15;
    CsS[q][n] = bc[(rowb + q) * 32 + 16 + n];
  }
  if (t < Q) ecs[t] = expf(cs[(((size_t)b * NCH + c) * NH + h) * Q + t]);
  float pv[16];
  #pragma unroll
  for (int k = 0; k < 4; ++k)
    *(float4*)&pv[k * 4] = *(const float4*)(prev + pb + (size_t)t * DS + k * 4);
  __syncthreads();
  for (int q = 0; q < Q; ++q) {
    float acc = 0.f;
    #pragma unroll
    for (int n = 0; n < DS; ++n) acc += CsS[q][n] * pv[n];
    const size_t idx = (rowb + q) * DI + h * HP + t;
    yb[idx] = f2bf(bf2f(yb[idx]) + ecs[q] * acc);
  }
}

// ---------------- gate with silu(z) + RMS norm (in place on bf16 y) ----------------
__global__ __launch_bounds__(256)
void gatenorm_kernel(const unsigned short* __restrict__ zx, const float* __restrict__ norm_w,
                     unsigned short* __restrict__ yb) {
  const size_t row = blockIdx.x;
  const int t = threadIdx.x;
  const unsigned short* zrow = zx + row * DP;
  unsigned short* yrow = yb + row * DI;
  const int d0 = t * 8;
  uint4 yv = *(const uint4*)(yrow + d0);
  uint4 zv = *(const uint4*)(zrow + d0);
  const unsigned short* ys = (const unsigned short*)&yv;
  const unsigned short* zs = (const unsigned short*)&zv;
  float v[8];
  float ss = 0.f;
  #pragma unroll
  for (int j = 0; j < 8; ++j) {
    float val = bf2f(ys[j]) * silu_f(bf2f(zs[j]));
    v[j] = val;
    ss += val * val;
  }
  #pragma unroll
  for (int off = 32; off > 0; off >>= 1) ss += __shfl_down(ss, off);
  __shared__ float red[4];
  if ((t & 63) == 0) red[t >> 6] = ss;
  __syncthreads();
  float tot = red[0] + red[1] + red[2] + red[3];
  float scale = rsqrtf(tot / (float)DI + 1e-5f);
  ushort4 o[2];
  unsigned short* op = (unsigned short*)o;
  #pragma unroll
  for (int j = 0; j < 8; ++j) op[j] = f2bf(v[j] * scale * norm_w[d0 + j]);
  *(uint4*)(yrow + d0) = *(uint4*)o;
}

// ---------------- launch ----------------
extern "C" void kernel_launch(void* const* d_in, const int* in_sizes, int n_in,
                              void* d_out, int out_size, void* d_ws, size_t ws_size,
                              hipStream_t stream) {
  const float* u       = (const float*)d_in[0];
  const float* W_in    = (const float*)d_in[1];
  const float* conv_w  = (const float*)d_in[2];
  const float* conv_b  = (const float*)d_in[3];
  const float* dt_bias = (const float*)d_in[4];
  const float* A_log   = (const float*)d_in[5];
  const float* Dp      = (const float*)d_in[6];
  const float* norm_w  = (const float*)d_in[7];
  const float* W_out   = (const float*)d_in[8];
  float* out = (float*)d_out;
  char* w = (char*)d_ws;

  unsigned short* zx  = (unsigned short*)(w + OFFB_ZX);
  float* bcb          = (float*)(w + OFFB_BC);
  float* dtb          = (float*)(w + OFFB_DT);
  float* csb          = (float*)(w + OFFB_CS);
  float* stb          = (float*)(w + OFFB_ST);
  unsigned short* yb  = (unsigned short*)(w + OFFB_Y);
  unsigned short* ub  = (unsigned short*)(w + OFFB_ST);  // u bf16, dead before states written
  unsigned short* wib = (unsigned short*)(w + OFFB_Y);   // W_in^T bf16, dead before yb written
  unsigned short* wob = (unsigned short*)(w + OFFB_WO);  // W_out^T bf16

  // 0a) u -> bf16 (NR x 1024)
  cvt_bf16<<<(NR * DM / 4 + 255) / 256, 256, 0, stream>>>(u, ub, (size_t)NR * DM / 4);
  // 0b) W_in [1024][4136] -> W_in^T bf16 [4352][1024], zero-padded rows
  transpose_cvt<<<dim3(DPT / 64, DM / 64), 256, 0, stream>>>(W_in, wib, DM, DP, DP);
  // 0c) W_out [2048][1024] -> W_out^T bf16 [1024][2048]
  transpose_cvt<<<dim3(DM / 64, DI / 64), 256, 0, stream>>>(W_out, wob, DI, DM, DM);
  // 1) zxbcdt = u @ W_in -> bf16  (M=16384, N=4136 in 17 256-tiles, K=1024)
  gemm256<true><<<dim3(DPT / 256, NR / 256), 512, 0, stream>>>(
      ub, wib, zx, NR, DP, DM, DP);
  // 2) conv + silu for B/C channels
  convbc_kernel<<<(NR * 32) / 256, 256, 0, stream>>>(zx, conv_w, conv_b, bcb);
  // 3) dt = softplus(raw + bias)
  dt_kernel<<<(NR * NH) / 256, 256, 0, stream>>>(zx, dt_bias, dtb);
  // 4) per-chunk: cumsum + x-conv + MFMA Y_diag(+Dx) + MFMA states
  chunk_kernel<<<dim3(NCH, NH, B_), 256, 0, stream>>>(zx, bcb, dtb, A_log, conv_w,
                                                      conv_b, Dp, csb, stb, yb);
  // 5) inter-chunk scan (in place)
  scan_kernel<<<dim3((HP * DS) / 256, NH, B_), 256, 0, stream>>>(stb, csb);
  // 6) Y_off accumulate
  yoff_kernel<<<dim3(NCH, NH, B_), 256, 0, stream>>>(bcb, csb, stb, yb);
  // 7) gate + RMS norm (in place)
  gatenorm_kernel<<<NR, 256, 0, stream>>>(zx, norm_w, yb);
  // 8) out = y @ W_out  (M=16384, N=1024, K=2048)
  gemm256<false><<<dim3(DM / 256, NR / 256), 512, 0, stream>>>(
      yb, wob, out, NR, DM, DI, DM);
}

// Round 4
// 532.818 us; speedup vs baseline: 1.0138x; 1.0138x over previous
//
#include <hip/hip_runtime.h>
#include <cstddef>
#include <cstdint>

// ---------------- problem constants ----------------
constexpr int DM = 1024;      // D_MODEL
constexpr int DI = 2048;      // D_INNER
constexpr int DS = 16;        // D_STATE
constexpr int NH = 8;         // NHEADS
constexpr int CD = 2080;      // CONV_DIM
constexpr int DP = 4136;      // D_IN_PROJ
constexpr int DPT = 4352;     // DP padded to 17*256 (W_in^T rows)
constexpr int Q  = 64;        // CHUNK
constexpr int B_ = 4;         // BATCH
constexpr int L_ = 4096;      // SEQLEN
constexpr int NCH = 64;       // chunks per sequence
constexpr int HP = 256;       // HEADDIM
constexpr int NR = B_ * L_;   // 16384 rows

// ---------------- workspace layout (BYTE offsets) ----------------
constexpr size_t AL(size_t x) { return (x + 255) & ~(size_t)255; }
constexpr size_t OFFB_ZX = 0;                                   // zxbcdt bf16 (NR x DP)
constexpr size_t OFFB_BC = AL(OFFB_ZX + (size_t)NR * DP * 2);   // conv'd B,C fp32 (NR x 32)
constexpr size_t OFFB_DT = AL(OFFB_BC + (size_t)NR * 32 * 4);   // dt fp32 (NR x NH)
constexpr size_t OFFB_CS = AL(OFFB_DT + (size_t)NR * NH * 4);   // cumsum fp32
constexpr size_t OFFB_ST = AL(OFFB_CS + (size_t)B_ * NCH * NH * Q * 4); // states fp32 (aliases u_bf16)
constexpr size_t OFFB_Y  = AL(OFFB_ST + (size_t)B_ * NCH * NH * HP * DS * 4); // y bf16 (aliases W_in^T bf16)
constexpr size_t OFFB_WO = AL(OFFB_Y + (size_t)NR * DI * 2);    // W_out^T bf16 (1024 x 2048)

__device__ __forceinline__ float silu_f(float x) { return x / (1.f + expf(-x)); }
__device__ __forceinline__ float bf2f(unsigned short v) {
  unsigned int u = ((unsigned int)v) << 16;
  return __builtin_bit_cast(float, u);
}
__device__ __forceinline__ unsigned short f2bf(float f) {
  unsigned int u = __builtin_bit_cast(unsigned int, f);
  u += 0x7FFFu + ((u >> 16) & 1u);   // round-to-nearest-even
  return (unsigned short)(u >> 16);
}

typedef __attribute__((ext_vector_type(8))) short bf16x8;   // 8 bf16 = 4 VGPRs
typedef __attribute__((ext_vector_type(4))) float f32x4;

__device__ __forceinline__ void bar() {
  asm volatile("" ::: "memory");
  __builtin_amdgcn_s_barrier();
  asm volatile("" ::: "memory");
}

// ================= 256x256 MFMA bf16 GEMM, m201-style 4-phase K-tile =================
// C[M,N] = A[M,K] @ Bt[N,K]^T.  BM=BN=256, 8 waves (2Mx4N), 512 threads.
// LDS: double-buffered K-tile of 64: buf[2][kk][mat] 16KB k-slices
// (256 rows x 32 k bf16) -> 128 KB, 1 block/CU, 2 waves/SIMD.
//
// Per K-tile tt (4 phases, phase p -> quadrant kk=p>>1, rq=p&1):
//   [ds_read THIS phase's frags: 8 (rq=0: A+B) or 4 (rq=1: A, B reused)]
//   [stage slice (kk, mat=rq) of tile tt+1: 2 x global_load_lds]
//   [rq==1: s_waitcnt vmcnt(4)  -- drains 2-3-phase-old loads, never 0]
//   barrier
//   setprio(1); 16 MFMA; setprio(0)
//   barrier
// Reads are issued BEFORE the barrier preceding their MFMA cluster (R3
// post-mortem: reads-after-barrier serialized the whole CU on lgkmcnt and
// capped MfmaUtil at 36%). Staging lags: every slice staged 3-4 phases before
// first read; waits only drain loads >=2 phases old. In-flight 4-8, never 0.
//
// LDS pair-line swizzle (R3, measured 0 conflicts): rows are 64B (32 bf16);
// a pair of rows = one 128B line with eight 16B slots s=(r&1)*4+c16;
// physical slot s' = s ^ ((r>>1)&7). Applied BOTH sides (rule #21):
// inverse-swizzled global source in stage(), swizzled address in frag().
template<bool OUT_BF16>
__global__ __launch_bounds__(512, 2)
void gemm256(const unsigned short* __restrict__ A, const unsigned short* __restrict__ Bt,
             void* __restrict__ Cout, int M, int N, int K, int ldc) {
  __shared__ __align__(16) unsigned short lds[2][2][2][256 * 32]; // [dbuf][kk][mat]
  const int t = threadIdx.x;
  const int w = t >> 6, l = t & 63;
  const int quad = l >> 4, lan = l & 15;
  const int wm = w >> 2, wn = w & 3;            // 2 x 4 wave grid
  // XCD-aware remap (bijective: gridDim.y % 8 == 0)
  const int ncol = gridDim.x;
  const int id = blockIdx.y * ncol + blockIdx.x;
  const int xcd = id & 7, slot0 = id >> 3;
  const int rpx = gridDim.y >> 3;
  const int row_g = xcd * rpx + slot0 / ncol;
  const int col_g = slot0 - (slot0 / ncol) * ncol;
  const int row0 = row_g * 256, col0 = col_g * 256;

  const int NT = K >> 6;                        // K-tiles of 64

  // stage one 16KB k-slice (kk half, mat 0=A / 1=B) of K-tile tt into buf[tt&1].
  auto stage = [&](int tt, int kk, int mat) {
    const int ss = (tt < NT) ? tt : 0;          // clamp: tail stages never read
    const unsigned short* G = mat ? Bt : A;
    const int b0 = mat ? col0 : row0;
    unsigned short* lb = lds[tt & 1][kk][mat];
    const int k0 = (ss << 6) + (kk << 5);
    #pragma unroll
    for (int i = 0; i < 2; ++i) {
      const int f = i * 512 + t;                // 16B chunk index 0..1023
      const int pair = f >> 3, sp = f & 7;      // 128B line, physical slot
      const int sl = sp ^ (pair & 7);           // logical slot
      const int r = pair * 2 + (sl >> 2);       // logical row 0..255
      const int c16 = sl & 3;                   // logical 16B chunk in row
      const unsigned short* gp = G + (size_t)(b0 + r) * K + k0 + (c16 << 3);
      __builtin_amdgcn_global_load_lds(
          (const __attribute__((address_space(1))) void*)gp,
          (__attribute__((address_space(3))) void*)(lb + (size_t)f * 8), 16, 0, 0);
    }
  };

  // swizzled fragment read: logical (row r, 16B-chunk q) of a k-slice
  auto frag = [&](const unsigned short* base, int r, int q) -> bf16x8 {
    const int pair = r >> 1;
    const int sp = (((r & 1) << 2) | q) ^ (pair & 7);
    return *(const bf16x8*)&base[pair * 64 + sp * 8];
  };

  f32x4 acc[2][4][4];
  #pragma unroll
  for (int rq = 0; rq < 2; ++rq)
    #pragma unroll
    for (int mi = 0; mi < 4; ++mi)
      #pragma unroll
      for (int ni = 0; ni < 4; ++ni)
        acc[rq][mi][ni] = (f32x4)(0.0f);

  // prologue: tile 0's four slices; drain Ak0,Bk0, leave Ak1,Bk1 in flight
  stage(0, 0, 0); stage(0, 0, 1);
  stage(0, 1, 0); stage(0, 1, 1);
  asm volatile("s_waitcnt vmcnt(4)" ::: "memory");
  bar();                                        // slices (kk=0) landed for all waves

  for (int tt = 0; tt < NT; ++tt) {
    const int cur = tt & 1;
    bf16x8 bf[4];                               // B frags, live across rq pair
    #pragma unroll
    for (int p = 0; p < 4; ++p) {
      const int kk = p >> 1, rq = p & 1;
      const unsigned short* As = lds[cur][kk][0];
      const unsigned short* Bs = lds[cur][kk][1];
      bf16x8 af[4];
      #pragma unroll
      for (int mi = 0; mi < 4; ++mi)
        af[mi] = frag(As, wm * 128 + rq * 64 + mi * 16 + lan, quad);
      if (rq == 0) {
        #pragma unroll
        for (int ni = 0; ni < 4; ++ni)
          bf[ni] = frag(Bs, wn * 64 + ni * 16 + lan, quad);
      }
      stage(tt + 1, kk, rq);                    // slice (kk, mat=rq) of next tile
      if (rq == 1)
        asm volatile("s_waitcnt vmcnt(4)" ::: "memory");
      bar();
      __builtin_amdgcn_s_setprio(1);
      #pragma unroll
      for (int mi = 0; mi < 4; ++mi)
        #pragma unroll
        for (int ni = 0; ni < 4; ++ni)
          acc[rq][mi][ni] = __builtin_amdgcn_mfma_f32_16x16x32_bf16(af[mi], bf[ni], acc[rq][mi][ni], 0, 0, 0);
      __builtin_amdgcn_s_setprio(0);
      bar();
    }
  }
  asm volatile("s_waitcnt vmcnt(0)" ::: "memory");    // drain tail LDS-DMA

  // ---- epilogue ----
  #pragma unroll
  for (int rq = 0; rq < 2; ++rq)
    #pragma unroll
    for (int mi = 0; mi < 4; ++mi) {
      const size_t rb = row0 + wm * 128 + rq * 64 + mi * 16 + quad * 4;
      #pragma unroll
      for (int ni = 0; ni < 4; ++ni) {
        const int colb = col0 + wn * 64 + ni * 16 + lan;
        if (colb < N) {
          if constexpr (OUT_BF16) {
            unsigned short* C = (unsigned short*)Cout;
            #pragma unroll
            for (int r = 0; r < 4; ++r)
              C[(rb + r) * (size_t)ldc + colb] = f2bf(acc[rq][mi][ni][r]);
          } else {
            float* C = (float*)Cout;
            #pragma unroll
            for (int r = 0; r < 4; ++r)
              C[(rb + r) * (size_t)ldc + colb] = acc[rq][mi][ni][r];
          }
        }
      }
    }
}

// ---------------- fp32 -> bf16 elementwise convert ----------------
__global__ __launch_bounds__(256)
void cvt_bf16(const float* __restrict__ src, unsigned short* __restrict__ dst, size_t n4) {
  const size_t i = ((size_t)blockIdx.x * 256 + threadIdx.x) * 4;
  if (i < n4 * 4) {
    float4 v = *(const float4*)(src + i);
    ushort4 o;
    o.x = f2bf(v.x); o.y = f2bf(v.y); o.z = f2bf(v.z); o.w = f2bf(v.w);
    *(ushort4*)(dst + i) = o;
  }
}

// ---------------- fp32 [R][C] -> bf16 transposed [Cpad][R], zero-fill c>=Cvalid ----------------
__global__ __launch_bounds__(256)
void transpose_cvt(const float* __restrict__ src, unsigned short* __restrict__ dst,
                   int R, int C, int Cvalid) {
  __shared__ float T[64][65];
  const int t = threadIdx.x;
  const int n0 = blockIdx.x * 64, k0 = blockIdx.y * 64;
  #pragma unroll
  for (int i = 0; i < 4; ++i) {
    int f = t + i * 256;
    int r = f >> 4, c4 = (f & 15) << 2;
    int n = n0 + c4;
    float4 v = make_float4(0.f, 0.f, 0.f, 0.f);
    if (n + 3 < Cvalid) {
      v = *(const float4*)(src + (size_t)(k0 + r) * C + n);
    } else {
      if (n + 0 < Cvalid) v.x = src[(size_t)(k0 + r) * C + n + 0];
      if (n + 1 < Cvalid) v.y = src[(size_t)(k0 + r) * C + n + 1];
      if (n + 2 < Cvalid) v.z = src[(size_t)(k0 + r) * C + n + 2];
      if (n + 3 < Cvalid) v.w = src[(size_t)(k0 + r) * C + n + 3];
    }
    T[r][c4 + 0] = v.x; T[r][c4 + 1] = v.y; T[r][c4 + 2] = v.z; T[r][c4 + 3] = v.w;
  }
  __syncthreads();
  #pragma unroll
  for (int i = 0; i < 4; ++i) {
    int f = t + i * 256;
    int c = f >> 4, r4 = (f & 15) << 2;
    ushort4 o;
    o.x = f2bf(T[r4 + 0][c]); o.y = f2bf(T[r4 + 1][c]);
    o.z = f2bf(T[r4 + 2][c]); o.w = f2bf(T[r4 + 3][c]);
    *(ushort4*)(dst + (size_t)(n0 + c) * R + k0 + r4) = o;
  }
}

// ---------------- conv+SiLU for the 32 B/C channels only ----------------
__global__ __launch_bounds__(256)
void convbc_kernel(const unsigned short* __restrict__ zx, const float* __restrict__ cw,
                   const float* __restrict__ cb, float* __restrict__ bc) {
  const int idx = blockIdx.x * 256 + threadIdx.x;   // < NR*32
  const int j = idx & 31;
  const int row = idx >> 5;
  const int l = row & (L_ - 1);
  const int cc = DI + j;                            // xBC channel 2048+j
  float a = cb[cc];
  #pragma unroll
  for (int k = 0; k < 4; ++k) {
    int ll = l - 3 + k;
    if (ll >= 0)
      a += bf2f(zx[(size_t)(row - 3 + k) * DP + (DI + DI + j)]) * cw[cc * 4 + k];
  }
  bc[(size_t)row * 32 + j] = silu_f(a);
}

// ---------------- dt = softplus(raw + bias) ----------------
__global__ __launch_bounds__(256)
void dt_kernel(const unsigned short* __restrict__ zx, const float* __restrict__ dt_bias,
               float* __restrict__ dt) {
  const int i = blockIdx.x * 256 + threadIdx.x;   // < NR*NH
  const int h = i & 7;
  const size_t row = (size_t)(i >> 3);
  float x = bf2f(zx[row * DP + (DI + CD) + h]) + dt_bias[h];
  dt[i] = (x > 20.f) ? x : log1pf(expf(x));
}

// ---------- per-(b,chunk,head): scan-cumsum + x-conv + MFMA Y_diag(+Dx) + MFMA states ----------
__global__ __launch_bounds__(256)
void chunk_kernel(const unsigned short* __restrict__ zx, const float* __restrict__ bc,
                  const float* __restrict__ dt, const float* __restrict__ A_log,
                  const float* __restrict__ cw, const float* __restrict__ cb,
                  const float* __restrict__ Dp, float* __restrict__ cs_out,
                  float* __restrict__ states, unsigned short* __restrict__ yb) {
  const int c = blockIdx.x, h = blockIdx.y, b = blockIdx.z;
  const int t = threadIdx.x;
  const int w = t >> 6, l = t & 63;
  const int quad = l >> 4, lan = l & 15;
  __shared__ float dtS[Q], csS[Q], ddS[Q];
  __shared__ float BsS[Q][DS + 1];
  __shared__ __align__(16) unsigned short Msd[Q][Q + 8];   // bf16 [q][s]
  __shared__ __align__(16) unsigned short BdT[DS][Q + 8];  // bf16 [n][q] = B[q][n]*dd[q]
  __shared__ __align__(16) char regionA[Q * (Q + 8) * 2];           // {CsS | xsT}
  __shared__ __align__(16) char regionB[Q * DS * 4 + Q * (Q + 8) * 2]; // {rawS | stS+ytS}
  float (*CsS)[DS]                 = (float(*)[DS])regionA;
  unsigned short (*xsT)[Q + 8]     = (unsigned short(*)[Q + 8])regionA;
  unsigned short (*rawS)[Q]        = (unsigned short(*)[Q])regionB;
  float (*stS)[DS]                 = (float(*)[DS])regionB;
  unsigned short (*ytS)[Q + 8]     = (unsigned short(*)[Q + 8])(regionB + Q * DS * 4);
  const size_t rowb = (size_t)b * L_ + (size_t)c * Q;

  // ---- dt load + parallel inclusive scan (wave 0) ----
  if (t < Q) {
    float dtv = dt[(rowb + t) * NH + h];
    dtS[t] = dtv;
    float s = dtv * (-expf(A_log[h]));
    #pragma unroll
    for (int off = 1; off < 64; off <<= 1) {
      float n = __shfl_up(s, off, 64);
      if (t >= off) s += n;
    }
    csS[t] = s;
    float slast = __shfl(s, 63, 64);
    ddS[t] = expf(slast - s) * dtv;          // decay_states * dt
    cs_out[(((size_t)b * NCH + c) * NH + h) * Q + t] = s;
  }
  for (int i = t; i < Q * DS; i += 256) {    // B/C loads (independent of scan)
    int q = i >> 4, n = i & 15;
    BsS[q][n] = bc[(rowb + q) * 32 + n];
    CsS[q][n] = bc[(rowb + q) * 32 + 16 + n];
  }
  __syncthreads();
  // ---- BdT + Msd (bf16) ----
  for (int i = t; i < DS * Q; i += 256) {
    int n = i & 15, q = i >> 4;
    BdT[n][q] = f2bf(BsS[q][n] * ddS[q]);
  }
  const float Dh = Dp[h];
  for (int i = t; i < Q * Q; i += 256) {
    int q = i >> 6, s = i & 63;
    float v = 0.f;
    if (s <= q) {
      float d = 0.f;
      #pragma unroll
      for (int n = 0; n < DS; ++n) d += CsS[q][n] * BsS[s][n];
      v = expf(csS[q] - csS[s]) * d * dtS[s];
      if (s == q) v += Dh;
    }
    Msd[q][s] = f2bf(v);
  }

  // ---- raw x prefetch (67 rows x 64 cols bf16 = 536 uint4 chunks) ----
  const int pch = l;                         // conv channel within tile (0..63)
  uint4 r0 = make_uint4(0, 0, 0, 0), r1 = make_uint4(0, 0, 0, 0), r2 = make_uint4(0, 0, 0, 0);
  {
    const int col0 = DI + h * HP;            // pt = 0
    const unsigned short* gb = zx + ((size_t)b * L_ + (c * Q - 3)) * DP + col0;
    if (c > 0 || t >= 24) r0 = *(const uint4*)(gb + (size_t)(t >> 3) * DP + (t & 7) * 8);
    r1 = *(const uint4*)(gb + (size_t)((t + 256) >> 3) * DP + (t & 7) * 8);
    if (t < 24) r2 = *(const uint4*)(gb + (size_t)((t + 512) >> 3) * DP + (t & 7) * 8);
  }

  for (int pt = 0; pt < 4; ++pt) {
    uint4* rw = (uint4*)rawS;
    rw[t] = r0; rw[t + 256] = r1;
    if (t < 24) rw[t + 512] = r2;
    __syncthreads();                          // B1: rawS ready
    // ---- conv+silu -> xsT[p][q] ----
    {
      const int cc = h * HP + pt * Q + pch;
      const float w0 = cw[cc * 4 + 0], w1 = cw[cc * 4 + 1];
      const float w2 = cw[cc * 4 + 2], w3 = cw[cc * 4 + 3];
      const float bias = cb[cc];
      const int q0 = w * 16;
      unsigned short ob[16];
      #pragma unroll
      for (int i2 = 0; i2 < 16; ++i2) {
        int q = q0 + i2;
        float a = bias + bf2f(rawS[q][pch]) * w0 + bf2f(rawS[q + 1][pch]) * w1
                       + bf2f(rawS[q + 2][pch]) * w2 + bf2f(rawS[q + 3][pch]) * w3;
        ob[i2] = f2bf(silu_f(a));
      }
      *(uint4*)&xsT[pch][q0 + 0] = *(uint4*)&ob[0];
      *(uint4*)&xsT[pch][q0 + 8] = *(uint4*)&ob[8];
    }
    // ---- prefetch next pt's raw tile (hides behind MFMA phase) ----
    if (pt < 3) {
      const int col0n = DI + h * HP + (pt + 1) * Q;
      const unsigned short* gb = zx + ((size_t)b * L_ + (c * Q - 3)) * DP + col0n;
      r0 = make_uint4(0, 0, 0, 0); r2 = make_uint4(0, 0, 0, 0);
      if (c > 0 || t >= 24) r0 = *(const uint4*)(gb + (size_t)(t >> 3) * DP + (t & 7) * 8);
      r1 = *(const uint4*)(gb + (size_t)((t + 256) >> 3) * DP + (t & 7) * 8);
      if (t < 24) r2 = *(const uint4*)(gb + (size_t)((t + 512) >> 3) * DP + (t & 7) * 8);
    }
    __syncthreads();                          // B2: xsT ready, rawS consumed
    // ---- MFMA phase ----
    bf16x8 xfrag[2];
    #pragma unroll
    for (int ks = 0; ks < 2; ++ks)
      xfrag[ks] = *(const bf16x8*)&xsT[w * 16 + lan][quad * 8 + ks * 32];
    {  // states[p][n] = sum_q x[p][q] * BdT[n][q] -> stS
      f32x4 sacc = (f32x4)(0.0f);
      #pragma unroll
      for (int ks = 0; ks < 2; ++ks) {
        bf16x8 bfr = *(const bf16x8*)&BdT[lan][quad * 8 + ks * 32];
        sacc = __builtin_amdgcn_mfma_f32_16x16x32_bf16(xfrag[ks], bfr, sacc, 0, 0, 0);
      }
      #pragma unroll
      for (int r = 0; r < 4; ++r)
        stS[w * 16 + quad * 4 + r][lan] = sacc[r];
    }
    {  // Y_diag[q][p] = sum_s Msd[q][s]*x[p][s] -> ytS
      #pragma unroll
      for (int mi = 0; mi < 4; ++mi) {
        f32x4 yac = (f32x4)(0.0f);
        #pragma unroll
        for (int ks = 0; ks < 2; ++ks) {
          bf16x8 am = *(const bf16x8*)&Msd[mi * 16 + lan][quad * 8 + ks * 32];
          yac = __builtin_amdgcn_mfma_f32_16x16x32_bf16(am, xfrag[ks], yac, 0, 0, 0);
        }
        #pragma unroll
        for (int r = 0; r < 4; ++r)
          ytS[mi * 16 + quad * 4 + r][w * 16 + lan] = f2bf(yac[r]);
      }
    }
    __syncthreads();                          // B3: staging tiles complete
    // ---- coalesced global stores ----
    {  // states tile: 64p x 16n fp32, fully contiguous 4KB
      const size_t stbase = ((((size_t)b * NCH + c) * NH + h) * HP + (size_t)pt * Q) * DS;
      ((float4*)(states + stbase))[t] = ((const float4*)&stS[0][0])[t];
    }
    {  // y tile: 64 rows x 128B
      const int colbase = h * HP + pt * Q;
      #pragma unroll
      for (int pass = 0; pass < 2; ++pass) {
        int q = pass * 32 + (t >> 3), p8 = (t & 7) * 8;
        *(uint4*)(yb + (rowb + q) * (size_t)DI + colbase + p8) = *(const uint4*)&ytS[q][p8];
      }
    }
    __syncthreads();                          // B4: stS/ytS reads done before next rawS write
  }
}

// ---------------- sequential inter-chunk scan (in place: states -> prev) ----------------
__global__ __launch_bounds__(256)
void scan_kernel(float* __restrict__ states, const float* __restrict__ cs) {
  const int pn = blockIdx.x * 256 + threadIdx.x;
  const int h = blockIdx.y, b = blockIdx.z;
  const size_t cstride = (size_t)NH * HP * DS;
  const size_t base = ((size_t)b * NCH * NH + h) * (size_t)(HP * DS) + pn;
  float carry = 0.f;
  for (int c = 0; c < NCH; ++c) {
    float dec = expf(cs[(((size_t)b * NCH + c) * NH + h) * Q + (Q - 1)]);
    float st = states[base + (size_t)c * cstride];
    states[base + (size_t)c * cstride] = carry;
    carry = dec * carry + st;
  }
}

// ---------------- Y_off accumulation into bf16 y ----------------
__global__ __launch_bounds__(256)
void yoff_kernel(const float* __restrict__ bc, const float* __restrict__ cs,
                 const float* __restrict__ prev, unsigned short* __restrict__ yb) {
  const int c = blockIdx.x, h = blockIdx.y, b = blockIdx.z;
  const int t = threadIdx.x;
  __shared__ __align__(16) float CsS[Q][DS];
  __shared__ float ecs[Q];
  const size_t rowb = (size_t)b * L_ + (size_t)c * Q;
  const size_t pb = (((size_t)b * NCH + c) * NH + h) * (size_t)(HP * DS);
  for (int i = t; i < Q * DS; i += 256) {
    int q = i >> 4, n = i & 15;
    CsS[q][n] = bc[(rowb + q) * 32 + 16 + n];
  }
  if (t < Q) ecs[t] = expf(cs[(((size_t)b * NCH + c) * NH + h) * Q + t]);
  float pv[16];
  #pragma unroll
  for (int k = 0; k < 4; ++k)
    *(float4*)&pv[k * 4] = *(const float4*)(prev + pb + (size_t)t * DS + k * 4);
  __syncthreads();
  for (int q = 0; q < Q; ++q) {
    float acc = 0.f;
    #pragma unroll
    for (int n = 0; n < DS; ++n) acc += CsS[q][n] * pv[n];
    const size_t idx = (rowb + q) * DI + h * HP + t;
    yb[idx] = f2bf(bf2f(yb[idx]) + ecs[q] * acc);
  }
}

// ---------------- gate with silu(z) + RMS norm (in place on bf16 y) ----------------
__global__ __launch_bounds__(256)
void gatenorm_kernel(const unsigned short* __restrict__ zx, const float* __restrict__ norm_w,
                     unsigned short* __restrict__ yb) {
  const size_t row = blockIdx.x;
  const int t = threadIdx.x;
  const unsigned short* zrow = zx + row * DP;
  unsigned short* yrow = yb + row * DI;
  const int d0 = t * 8;
  uint4 yv = *(const uint4*)(yrow + d0);
  uint4 zv = *(const uint4*)(zrow + d0);
  const unsigned short* ys = (const unsigned short*)&yv;
  const unsigned short* zs = (const unsigned short*)&zv;
  float v[8];
  float ss = 0.f;
  #pragma unroll
  for (int j = 0; j < 8; ++j) {
    float val = bf2f(ys[j]) * silu_f(bf2f(zs[j]));
    v[j] = val;
    ss += val * val;
  }
  #pragma unroll
  for (int off = 32; off > 0; off >>= 1) ss += __shfl_down(ss, off);
  __shared__ float red[4];
  if ((t & 63) == 0) red[t >> 6] = ss;
  __syncthreads();
  float tot = red[0] + red[1] + red[2] + red[3];
  float scale = rsqrtf(tot / (float)DI + 1e-5f);
  ushort4 o[2];
  unsigned short* op = (unsigned short*)o;
  #pragma unroll
  for (int j = 0; j < 8; ++j) op[j] = f2bf(v[j] * scale * norm_w[d0 + j]);
  *(uint4*)(yrow + d0) = *(uint4*)o;
}

// ---------------- launch ----------------
extern "C" void kernel_launch(void* const* d_in, const int* in_sizes, int n_in,
                              void* d_out, int out_size, void* d_ws, size_t ws_size,
                              hipStream_t stream) {
  const float* u       = (const float*)d_in[0];
  const float* W_in    = (const float*)d_in[1];
  const float* conv_w  = (const float*)d_in[2];
  const float* conv_b  = (const float*)d_in[3];
  const float* dt_bias = (const float*)d_in[4];
  const float* A_log   = (const float*)d_in[5];
  const float* Dp      = (const float*)d_in[6];
  const float* norm_w  = (const float*)d_in[7];
  const float* W_out   = (const float*)d_in[8];
  float* out = (float*)d_out;
  char* w = (char*)d_ws;

  unsigned short* zx  = (unsigned short*)(w + OFFB_ZX);
  float* bcb          = (float*)(w + OFFB_BC);
  float* dtb          = (float*)(w + OFFB_DT);
  float* csb          = (float*)(w + OFFB_CS);
  float* stb          = (float*)(w + OFFB_ST);
  unsigned short* yb  = (unsigned short*)(w + OFFB_Y);
  unsigned short* ub  = (unsigned short*)(w + OFFB_ST);  // u bf16, dead before states written
  unsigned short* wib = (unsigned short*)(w + OFFB_Y);   // W_in^T bf16, dead before yb written
  unsigned short* wob = (unsigned short*)(w + OFFB_WO);  // W_out^T bf16

  // 0a) u -> bf16 (NR x 1024)
  cvt_bf16<<<(NR * DM / 4 + 255) / 256, 256, 0, stream>>>(u, ub, (size_t)NR * DM / 4);
  // 0b) W_in [1024][4136] -> W_in^T bf16 [4352][1024], zero-padded rows
  transpose_cvt<<<dim3(DPT / 64, DM / 64), 256, 0, stream>>>(W_in, wib, DM, DP, DP);
  // 0c) W_out [2048][1024] -> W_out^T bf16 [1024][2048]
  transpose_cvt<<<dim3(DM / 64, DI / 64), 256, 0, stream>>>(W_out, wob, DI, DM, DM);
  // 1) zxbcdt = u @ W_in -> bf16  (M=16384, N=4136 in 17 256-tiles, K=1024)
  gemm256<true><<<dim3(DPT / 256, NR / 256), 512, 0, stream>>>(
      ub, wib, zx, NR, DP, DM, DP);
  // 2) conv + silu for B/C channels
  convbc_kernel<<<(NR * 32) / 256, 256, 0, stream>>>(zx, conv_w, conv_b, bcb);
  // 3) dt = softplus(raw + bias)
  dt_kernel<<<(NR * NH) / 256, 256, 0, stream>>>(zx, dt_bias, dtb);
  // 4) per-chunk: cumsum + x-conv + MFMA Y_diag(+Dx) + MFMA states
  chunk_kernel<<<dim3(NCH, NH, B_), 256, 0, stream>>>(zx, bcb, dtb, A_log, conv_w,
                                                      conv_b, Dp, csb, stb, yb);
  // 5) inter-chunk scan (in place)
  scan_kernel<<<dim3((HP * DS) / 256, NH, B_), 256, 0, stream>>>(stb, csb);
  // 6) Y_off accumulate
  yoff_kernel<<<dim3(NCH, NH, B_), 256, 0, stream>>>(bcb, csb, stb, yb);
  // 7) gate + RMS norm (in place)
  gatenorm_kernel<<<NR, 256, 0, stream>>>(zx, norm_w, yb);
  // 8) out = y @ W_out  (M=16384, N=1024, K=2048)
  gemm256<false><<<dim3(DM / 256, NR / 256), 512, 0, stream>>>(
      yb, wob, out, NR, DM, DI, DM);
}